// Round 14
// baseline (218.671 us; speedup 1.0000x reference)
//
#include <hip/hip_runtime.h>
#include <hip/hip_bf16.h>

typedef __bf16 bf16;
typedef __attribute__((ext_vector_type(4))) __bf16 bf16x4;
typedef __attribute__((ext_vector_type(8))) __bf16 bf16x8;
typedef __attribute__((ext_vector_type(4))) float f32x4;
typedef __attribute__((ext_vector_type(16))) float f32x16;

#define B_ 8
#define N_ 1024
#define M_ 1024
#define H_ 8
#define ROWS_ (B_ * N_)   // 8192

__device__ __forceinline__ f32x4 mfma16(bf16x8 a, bf16x8 b, f32x4 c) {
    return __builtin_amdgcn_mfma_f32_16x16x32_bf16(a, b, c, 0, 0, 0);
}
__device__ __forceinline__ f32x16 mfma32(bf16x8 a, bf16x8 b, f32x16 c) {
    return __builtin_amdgcn_mfma_f32_32x32x16_bf16(a, b, c, 0, 0, 0);
}

__device__ __forceinline__ void glds16(const void* g, void* l) {
    __builtin_amdgcn_global_load_lds((const __attribute__((address_space(1))) void*)g,
                                     (__attribute__((address_space(3))) void*)l, 16, 0, 0);
}

// ---------------- prep: x/y -> bf16 (blocks 0..8191), 6 weight transposes (blocks 8192..8575) ----------------
__global__ __launch_bounds__(256) void prep(const float* __restrict__ x, const float* __restrict__ y,
                                            bf16* __restrict__ Xb, bf16* __restrict__ Yb,
                                            const float* W0, const float* W1, const float* W2,
                                            const float* W3, const float* W4, const float* W5,
                                            bf16* T0, bf16* T1, bf16* T2, bf16* T3, bf16* T4, bf16* T5) {
    __shared__ float t[64][65];
    int bid = blockIdx.x;
    if (bid < 8192) {
        int i = bid * 256 + threadIdx.x;   // float4 groups, 2M total
        const float4* s;
        bf16x4* d;
        int j;
        if (i < 1048576) { s = (const float4*)x; d = (bf16x4*)Xb; j = i; }
        else             { s = (const float4*)y; d = (bf16x4*)Yb; j = i - 1048576; }
        float4 f = s[j];
        bf16x4 o = {(bf16)f.x, (bf16)f.y, (bf16)f.z, (bf16)f.w};
        d[j] = o;
        return;
    }
    int wb = bid - 8192;                  // 0..383
    const float* srcs[6] = {W0, W1, W2, W3, W4, W5};
    bf16* dsts[6] = {T0, T1, T2, T3, T4, T5};
    const float* W = srcs[wb >> 6];
    bf16* Wt = dsts[wb >> 6];
    int tile = wb & 63;
    int k0 = (tile >> 3) * 64, n0 = (tile & 7) * 64;
    int tx = threadIdx.x & 63, ty = threadIdx.x >> 6;
#pragma unroll
    for (int j = 0; j < 16; ++j)
        t[ty + j * 4][tx] = W[(size_t)(k0 + ty + j * 4) * 512 + n0 + tx];
    __syncthreads();
#pragma unroll
    for (int j = 0; j < 16; ++j)
        Wt[(size_t)(n0 + ty + j * 4) * 512 + k0 + tx] = (bf16)t[tx][ty + j * 4];
}

// ---------------- GEMM core: 128(A-rows) x 64(Bt-rows) tile, BK=64, 4 waves (32x64 each), 32x32x16 MFMA ----
// double-buffered LDS staging (2 x 16KB A + 2 x 8KB B): 1 barrier per K-step.
// A-frag: row=lane&31, k=(lane>>5)*8+j. B-frag: col=lane&31, same k.
// C/D: col=lane&31, row=(reg&3)+8*(reg>>2)+4*(lane>>5)  [verified m74/m101]
__device__ __forceinline__ void gemm_core(const bf16* __restrict__ A, const bf16* __restrict__ Bt,
                                          int row0, int col0, char* AsB, char* BsB, f32x16 acc[2]) {
    int tid = threadIdx.x, wave = tid >> 6, lane = tid & 63;
    int l31 = lane & 31, kh = lane >> 5;
    const bf16 *Asrc[4], *Bsrc[2];
#pragma unroll
    for (int s = 0; s < 4; ++s) {
        int c = tid + s * 256, r = c >> 3, bk = (c & 7) ^ (r & 7);
        Asrc[s] = A + (size_t)(row0 + r) * 512 + bk * 8;
    }
#pragma unroll
    for (int s = 0; s < 2; ++s) {
        int c = tid + s * 256, r = c >> 3, bk = (c & 7) ^ (r & 7);
        Bsrc[s] = Bt + (size_t)(col0 + r) * 512 + bk * 8;
    }
    int wb = wave * 1024;
    // prologue: stage tile 0 into buffer 0
#pragma unroll
    for (int s = 0; s < 4; ++s) glds16(Asrc[s], AsB + s * 4096 + wb);
#pragma unroll
    for (int s = 0; s < 2; ++s) glds16(Bsrc[s], BsB + s * 4096 + wb);
#pragma unroll
    for (int it = 0; it < 8; ++it) {
        __syncthreads();   // implicit vmcnt(0): tile `it` resident
        const char* Ac = AsB + (it & 1) * 16384;
        const char* Bc = BsB + (it & 1) * 8192;
        if (it < 7) {
            char* An = AsB + ((it + 1) & 1) * 16384;
            char* Bn = BsB + ((it + 1) & 1) * 8192;
            int k0 = (it + 1) * 64;
#pragma unroll
            for (int s = 0; s < 4; ++s) glds16(Asrc[s] + k0, An + s * 4096 + wb);
#pragma unroll
            for (int s = 0; s < 2; ++s) glds16(Bsrc[s] + k0, Bn + s * 4096 + wb);
        }
        bf16x8 af[4], bfr[2][4];
        int arow = wave * 32 + l31;
#pragma unroll
        for (int ks = 0; ks < 4; ++ks)
            af[ks] = *(const bf16x8*)(Ac + (arow * 8 + ((ks * 2 + kh) ^ (arow & 7))) * 16);
#pragma unroll
        for (int ct = 0; ct < 2; ++ct) {
            int col = ct * 32 + l31;
#pragma unroll
            for (int ks = 0; ks < 4; ++ks)
                bfr[ct][ks] = *(const bf16x8*)(Bc + (col * 8 + ((ks * 2 + kh) ^ (col & 7))) * 16);
        }
#pragma unroll
        for (int ct = 0; ct < 2; ++ct)
#pragma unroll
            for (int ks = 0; ks < 4; ++ks)
                acc[ct] = mfma32(af[ks], bfr[ct][ks], acc[ct]);
    }
}

// fused QKV projections. z=0: q = (Xb@Wq)*cl (pre-scaled); z=1: k = Yb@Wk; z=2: Vt = (Yb@Wv)^T
__global__ __launch_bounds__(256, 3) void proj_qkv(const bf16* __restrict__ Xb, const bf16* __restrict__ Yb,
                                                   const bf16* __restrict__ Wqt, const bf16* __restrict__ Wkt,
                                                   const bf16* __restrict__ Wvt,
                                                   bf16* __restrict__ qb, bf16* __restrict__ kb,
                                                   bf16* __restrict__ Vt) {
    __shared__ char AsB[2 * 16384];
    __shared__ char BsB[2 * 8192];
    int z = blockIdx.z;
    const bf16 *A, *Bt;
    int row0, col0;
    if (z == 0)      { A = Xb;  Bt = Wqt; row0 = blockIdx.x * 128; col0 = blockIdx.y * 64; }
    else if (z == 1) { A = Yb;  Bt = Wkt; row0 = blockIdx.x * 128; col0 = blockIdx.y * 64; }
    else { A = Wvt; Bt = Yb; int flat = blockIdx.y * 64 + blockIdx.x; row0 = (flat & 3) * 128; col0 = (flat >> 2) * 64; }
    f32x16 acc[2];
#pragma unroll
    for (int i = 0; i < 2; ++i)
#pragma unroll
        for (int r = 0; r < 16; ++r) acc[i][r] = 0.f;
    gemm_core(A, Bt, row0, col0, AsB, BsB, acc);
    int wave = threadIdx.x >> 6, lane = threadIdx.x & 63;
    int l31 = lane & 31, kh = lane >> 5;
    bf16* dst = (z == 0) ? qb : kb;
    const float cl = 0.06376373228f;    // (1/sqrt(512)) * log2(e)
    float sc = (z == 0) ? cl : 1.0f;
#pragma unroll
    for (int ct = 0; ct < 2; ++ct) {
        int col = col0 + ct * 32 + l31;
#pragma unroll
        for (int r = 0; r < 16; ++r) {
            int row = row0 + wave * 32 + (r & 3) + 8 * (r >> 2) + 4 * kh;
            bf16 v = (bf16)(acc[ct][r] * sc);
            if (z < 2) dst[(size_t)row * 512 + col] = v;
            else Vt[(size_t)((col >> 10) * 512 + row) * 1024 + (col & 1023)] = v;
        }
    }
}

// all outputs bf16. BIAS: add bias[col]; RELU: max(0,.);
// RESID: 0 none, 1 += fp32 resid[row*512+col], 2 += bf16 resid[row*512+col]
template <int BIAS, int RELU, int RESID>
__global__ __launch_bounds__(256, 3) void gemm_bt(const bf16* __restrict__ A, const bf16* __restrict__ Bt,
                                                  const float* __restrict__ bias,
                                                  const void* __restrict__ resid,
                                                  bf16* __restrict__ Cout) {
    __shared__ char AsB[2 * 16384];
    __shared__ char BsB[2 * 8192];
    int row0 = blockIdx.x * 128, col0 = blockIdx.y * 64;
    f32x16 acc[2];
#pragma unroll
    for (int i = 0; i < 2; ++i)
#pragma unroll
        for (int r = 0; r < 16; ++r) acc[i][r] = 0.f;
    gemm_core(A, Bt, row0, col0, AsB, BsB, acc);
    int wave = threadIdx.x >> 6, lane = threadIdx.x & 63;
    int l31 = lane & 31, kh = lane >> 5;
#pragma unroll
    for (int ct = 0; ct < 2; ++ct) {
        int col = col0 + ct * 32 + l31;
        float bv = BIAS ? bias[col] : 0.0f;
#pragma unroll
        for (int r = 0; r < 16; ++r) {
            int row = row0 + wave * 32 + (r & 3) + 8 * (r >> 2) + 4 * kh;
            float v = acc[ct][r] + bv;
            if (RESID == 1) v += ((const float*)resid)[(size_t)row * 512 + col];
            if (RESID == 2) v += (float)((const bf16*)resid)[(size_t)row * 512 + col];
            if (RELU) v = fmaxf(v, 0.0f);
            Cout[(size_t)row * 512 + col] = (bf16)v;
        }
    }
}

// ---------------- attention (R9 shape: best measured) ----------------
// 512 thr (8 waves, wave owns 16 q rows), Q-tile 128, grid 512, K/V double-buffered.
// Q pre-scaled by log2(e)/sqrt(512); lsum via ones-MFMA. bid = ntile*64 + (b*8+h).
__global__ __launch_bounds__(512, 2) void attn(const bf16* __restrict__ Q, const bf16* __restrict__ Kb,
                                               const bf16* __restrict__ Vt, const int* __restrict__ ymask,
                                               bf16* __restrict__ att) {
    __shared__ bf16 Ks[2][64 * 64];     // [key][d], swizzled (2 x 8 KB)
    __shared__ bf16 Vs[2][64 * 64];     // [d][m], swizzled (2 x 8 KB)
    __shared__ bf16 Ps[8][16 * 72];     // per-wave P [q][key], stride 72 (18 KB)
    __shared__ float fmk[1024];         // mask addend per key (4 KB)

    int bid = blockIdx.x;
    int bh = bid & 63, n0 = (bid >> 6) * 128;
    int b = bh >> 3, h = bh & 7;
    int tid = threadIdx.x, wave = tid >> 6, lane = tid & 63;
    int lr = lane & 15, q4 = lane >> 4;

    const int* ymb = ymask + (b << 10);
    fmk[tid]       = ymb[tid]       ? -1e38f : 0.0f;
    fmk[tid + 512] = ymb[tid + 512] ? -1e38f : 0.0f;

    const bf16* qp = Q + (size_t)((b << 10) + n0 + wave * 16 + lr) * 512 + h * 64 + q4 * 8;
    bf16x8 aq0 = *(const bf16x8*)qp;
    bf16x8 aq1 = *(const bf16x8*)(qp + 32);

    bf16 one1 = (bf16)1.0f;
    bf16x8 ones = {one1, one1, one1, one1, one1, one1, one1, one1};

    int r = tid >> 3, bk = (tid & 7) ^ (r & 7);
    const bf16* Ksrc = Kb + (size_t)((b << 10) + r) * 512 + h * 64 + bk * 8;
    const bf16* Vsrc = Vt + (size_t)(b * 512 + h * 64 + r) * 1024 + bk * 8;
    int ldso = tid * 16;

    const f32x4 zv = {0.f, 0.f, 0.f, 0.f};
    f32x4 O[4] = {zv, zv, zv, zv};
    f32x4 O4 = zv;

    glds16(Ksrc, (char*)Ks[0] + ldso);
    glds16(Vsrc, (char*)Vs[0] + ldso);

    for (int it = 0; it < 16; ++it) {
        __syncthreads();
        const char* K_ = (const char*)Ks[it & 1];
        const char* V_ = (const char*)Vs[it & 1];
        if (it < 15) {
            size_t m1 = (size_t)(it + 1) * 64;
            glds16(Ksrc + m1 * 512, (char*)Ks[(it + 1) & 1] + ldso);
            glds16(Vsrc + m1, (char*)Vs[(it + 1) & 1] + ldso);
        }

#pragma unroll
        for (int nt = 0; nt < 4; ++nt) {
            int krow = nt * 16 + lr;
            bf16x8 kf0 = *(const bf16x8*)(K_ + (krow * 8 + (q4 ^ (krow & 7))) * 16);
            bf16x8 kf1 = *(const bf16x8*)(K_ + (krow * 8 + ((4 + q4) ^ (krow & 7))) * 16);
            float fm = fmk[it * 64 + krow];
            f32x4 s = {fm, fm, fm, fm};
            s = mfma16(aq0, kf0, s);
            s = mfma16(aq1, kf1, s);
#pragma unroll
            for (int rr = 0; rr < 4; ++rr)
                Ps[wave][(q4 * 4 + rr) * 72 + krow] = (bf16)exp2f(s[rr]);
        }
        bf16x8 ap0 = *(const bf16x8*)&Ps[wave][lr * 72 + q4 * 8];
        bf16x8 ap1 = *(const bf16x8*)&Ps[wave][lr * 72 + 32 + q4 * 8];
        O4 = mfma16(ap0, ones, O4);
        O4 = mfma16(ap1, ones, O4);
#pragma unroll
        for (int dt = 0; dt < 4; ++dt) {
            int vrow = dt * 16 + lr;
            bf16x8 vf0 = *(const bf16x8*)(V_ + (vrow * 8 + (q4 ^ (vrow & 7))) * 16);
            bf16x8 vf1 = *(const bf16x8*)(V_ + (vrow * 8 + ((4 + q4) ^ (vrow & 7))) * 16);
            O[dt] = mfma16(ap0, vf0, O[dt]);
            O[dt] = mfma16(ap1, vf1, O[dt]);
        }
    }

    float inv[4];
#pragma unroll
    for (int rr = 0; rr < 4; ++rr)
        inv[rr] = (O4[rr] > 0.0f) ? (1.0f / O4[rr]) : 0.0f;
#pragma unroll
    for (int dt = 0; dt < 4; ++dt)
#pragma unroll
        for (int rr = 0; rr < 4; ++rr) {
            int row = n0 + wave * 16 + q4 * 4 + rr;
            att[(size_t)((b << 10) + row) * 512 + h * 64 + dt * 16 + lr] =
                (bf16)(O[dt][rr] * inv[rr]);
        }
}

// ---------------- LayerNorms (128 thr = 1 row; single bf16 input) ----------------
// ln1: obf = LN(o1)  (o1 = x + att@Wo, bf16, residual fused in Wo epilogue)
__global__ __launch_bounds__(128) void ln1_k(const bf16* __restrict__ O1,
                                             const float* __restrict__ g, const float* __restrict__ be,
                                             bf16* __restrict__ Obf) {
    int row = blockIdx.x, t = threadIdx.x;
    bf16x4 av = ((const bf16x4*)(O1 + (size_t)row * 512))[t];
    float4 o = {(float)av.x, (float)av.y, (float)av.z, (float)av.w};
    float s = o.x + o.y + o.z + o.w;
    float sq = o.x * o.x + o.y * o.y + o.z * o.z + o.w * o.w;
#pragma unroll
    for (int off = 1; off < 64; off <<= 1) { s += __shfl_xor(s, off); sq += __shfl_xor(sq, off); }
    __shared__ float ls[2], lq[2];
    if ((t & 63) == 0) { ls[t >> 6] = s; lq[t >> 6] = sq; }
    __syncthreads();
    s = ls[0] + ls[1]; sq = lq[0] + lq[1];
    float mu = s * (1.0f / 512.0f);
    float var = sq * (1.0f / 512.0f) - mu * mu;
    float rs = rsqrtf(var + 1e-5f);
    float4 gv = ((const float4*)g)[t];
    float4 bv = ((const float4*)be)[t];
    bf16x4 b4 = {(bf16)((o.x - mu) * rs * gv.x + bv.x), (bf16)((o.y - mu) * rs * gv.y + bv.y),
                 (bf16)((o.z - mu) * rs * gv.z + bv.z), (bf16)((o.w - mu) * rs * gv.w + bv.w)};
    ((bf16x4*)(Obf + (size_t)row * 512))[t] = b4;
}

// ln2: out = mask ? 0 : LN(S)  (S = obf + ff, bf16, residual fused in FF2 epilogue; fp32 out)
__global__ __launch_bounds__(128) void ln2_k(const bf16* __restrict__ S,
                                             const float* __restrict__ g, const float* __restrict__ be,
                                             const int* __restrict__ xmask, float* __restrict__ out) {
    int row = blockIdx.x, t = threadIdx.x;
    bf16x4 xv = ((const bf16x4*)(S + (size_t)row * 512))[t];
    float4 o = {(float)xv.x, (float)xv.y, (float)xv.z, (float)xv.w};
    float s = o.x + o.y + o.z + o.w;
    float sq = o.x * o.x + o.y * o.y + o.z * o.z + o.w * o.w;
#pragma unroll
    for (int off = 1; off < 64; off <<= 1) { s += __shfl_xor(s, off); sq += __shfl_xor(sq, off); }
    __shared__ float ls[2], lq[2];
    if ((t & 63) == 0) { ls[t >> 6] = s; lq[t >> 6] = sq; }
    __syncthreads();
    s = ls[0] + ls[1]; sq = lq[0] + lq[1];
    float mu = s * (1.0f / 512.0f);
    float var = sq * (1.0f / 512.0f) - mu * mu;
    float rs = rsqrtf(var + 1e-5f);
    int msk = xmask[row];
    float4 gv = ((const float4*)g)[t];
    float4 bv = ((const float4*)be)[t];
    float4 r4 = {(o.x - mu) * rs * gv.x + bv.x, (o.y - mu) * rs * gv.y + bv.y,
                 (o.z - mu) * rs * gv.z + bv.z, (o.w - mu) * rs * gv.w + bv.w};
    if (msk) r4 = {0.f, 0.f, 0.f, 0.f};
    ((float4*)(out + (size_t)row * 512))[t] = r4;
}

// ---------------- launcher ----------------
extern "C" void kernel_launch(void* const* d_in, const int* in_sizes, int n_in,
                              void* d_out, int out_size, void* d_ws, size_t ws_size,
                              hipStream_t stream) {
    const float* x   = (const float*)d_in[0];
    const float* y   = (const float*)d_in[1];
    const int*   xm  = (const int*)d_in[2];
    const int*   ym  = (const int*)d_in[3];
    const float* Wq  = (const float*)d_in[4];
    const float* Wk  = (const float*)d_in[5];
    const float* Wv  = (const float*)d_in[6];
    const float* Wo  = (const float*)d_in[7];
    const float* W1  = (const float*)d_in[8];
    const float* b1  = (const float*)d_in[9];
    const float* W2  = (const float*)d_in[10];
    const float* b2  = (const float*)d_in[11];
    const float* g1  = (const float*)d_in[12];
    const float* be1 = (const float*)d_in[13];
    const float* g2  = (const float*)d_in[14];
    const float* be2 = (const float*)d_in[15];

    char* ws = (char*)d_ws;
    const size_t WT_SZ  = 512 * 512 * sizeof(bf16);             // 512 KB
    const size_t XB_SZ  = (size_t)ROWS_ * 512 * sizeof(bf16);   // 8 MB

    bf16* Wqt = (bf16*)(ws + 0 * WT_SZ);
    bf16* Wkt = (bf16*)(ws + 1 * WT_SZ);
    bf16* Wvt = (bf16*)(ws + 2 * WT_SZ);
    bf16* Wot = (bf16*)(ws + 3 * WT_SZ);
    bf16* W1t = (bf16*)(ws + 4 * WT_SZ);
    bf16* W2t = (bf16*)(ws + 5 * WT_SZ);
    size_t off = 6 * WT_SZ;
    bf16* Xb  = (bf16*)(ws + off); off += XB_SZ;
    bf16* Yb  = (bf16*)(ws + off); off += XB_SZ;
    bf16* qb  = (bf16*)(ws + off); off += XB_SZ;
    bf16* kb  = (bf16*)(ws + off); off += XB_SZ;
    bf16* Vt  = (bf16*)(ws + off); off += XB_SZ;
    // aliases of dead buffers:
    bf16* attb = Xb;   // Xb dead after q projection
    bf16* o1   = kb;   // kb dead after attention:  o1 = x + att@Wo (bf16)
    bf16* obf  = qb;   // qb dead after attention:  obf = LN1(o1)
    bf16* hb   = Yb;   // Yb dead after projections
    bf16* fb   = Vt;   // Vt dead after attention:  fb = obf + FF2-out

    prep<<<8576, 256, 0, stream>>>(x, y, Xb, Yb, Wq, Wk, Wv, Wo, W1, W2,
                                   Wqt, Wkt, Wvt, Wot, W1t, W2t);

    proj_qkv<<<dim3(64, 8, 3), 256, 0, stream>>>(Xb, Yb, Wqt, Wkt, Wvt, qb, kb, Vt);

    attn<<<512, 512, 0, stream>>>(qb, kb, Vt, ym, attb);

    dim3 gg(64, 8);
    gemm_bt<0, 0, 1><<<gg, 256, 0, stream>>>(attb, Wot, nullptr, x, o1);      // o1 = x + att@Wo
    ln1_k<<<ROWS_, 128, 0, stream>>>(o1, g1, be1, obf);                       // obf = LN1(o1)
    gemm_bt<1, 1, 0><<<gg, 256, 0, stream>>>(obf, W1t, b1, nullptr, hb);      // hb = relu(obf@W1+b1)
    gemm_bt<1, 0, 2><<<gg, 256, 0, stream>>>(hb, W2t, b2, obf, fb);           // fb = obf + hb@W2+b2
    ln2_k<<<ROWS_, 128, 0, stream>>>(fb, g2, be2, xm, (float*)d_out);         // out = mask?0:LN2(fb)
}

// Round 15
// 208.570 us; speedup vs baseline: 1.0484x; 1.0484x over previous
//
#include <hip/hip_runtime.h>
#include <hip/hip_bf16.h>

typedef __bf16 bf16;
typedef __attribute__((ext_vector_type(4))) __bf16 bf16x4;
typedef __attribute__((ext_vector_type(8))) __bf16 bf16x8;
typedef __attribute__((ext_vector_type(4))) float f32x4;
typedef __attribute__((ext_vector_type(16))) float f32x16;

#define B_ 8
#define N_ 1024
#define M_ 1024
#define H_ 8
#define ROWS_ (B_ * N_)   // 8192

__device__ __forceinline__ f32x4 mfma16(bf16x8 a, bf16x8 b, f32x4 c) {
    return __builtin_amdgcn_mfma_f32_16x16x32_bf16(a, b, c, 0, 0, 0);
}
__device__ __forceinline__ f32x16 mfma32(bf16x8 a, bf16x8 b, f32x16 c) {
    return __builtin_amdgcn_mfma_f32_32x32x16_bf16(a, b, c, 0, 0, 0);
}

__device__ __forceinline__ void glds16(const void* g, void* l) {
    __builtin_amdgcn_global_load_lds((const __attribute__((address_space(1))) void*)g,
                                     (__attribute__((address_space(3))) void*)l, 16, 0, 0);
}

// ---------------- prep: x/y -> bf16 (blocks 0..8191), 6 weight transposes (blocks 8192..8575) ----------------
__global__ __launch_bounds__(256) void prep(const float* __restrict__ x, const float* __restrict__ y,
                                            bf16* __restrict__ Xb, bf16* __restrict__ Yb,
                                            const float* W0, const float* W1, const float* W2,
                                            const float* W3, const float* W4, const float* W5,
                                            bf16* T0, bf16* T1, bf16* T2, bf16* T3, bf16* T4, bf16* T5) {
    __shared__ float t[64][65];
    int bid = blockIdx.x;
    if (bid < 8192) {
        int i = bid * 256 + threadIdx.x;   // float4 groups, 2M total
        const float4* s;
        bf16x4* d;
        int j;
        if (i < 1048576) { s = (const float4*)x; d = (bf16x4*)Xb; j = i; }
        else             { s = (const float4*)y; d = (bf16x4*)Yb; j = i - 1048576; }
        float4 f = s[j];
        bf16x4 o = {(bf16)f.x, (bf16)f.y, (bf16)f.z, (bf16)f.w};
        d[j] = o;
        return;
    }
    int wb = bid - 8192;                  // 0..383
    const float* srcs[6] = {W0, W1, W2, W3, W4, W5};
    bf16* dsts[6] = {T0, T1, T2, T3, T4, T5};
    const float* W = srcs[wb >> 6];
    bf16* Wt = dsts[wb >> 6];
    int tile = wb & 63;
    int k0 = (tile >> 3) * 64, n0 = (tile & 7) * 64;
    int tx = threadIdx.x & 63, ty = threadIdx.x >> 6;
#pragma unroll
    for (int j = 0; j < 16; ++j)
        t[ty + j * 4][tx] = W[(size_t)(k0 + ty + j * 4) * 512 + n0 + tx];
    __syncthreads();
#pragma unroll
    for (int j = 0; j < 16; ++j)
        Wt[(size_t)(n0 + ty + j * 4) * 512 + k0 + tx] = (bf16)t[tx][ty + j * 4];
}

// ---------------- GEMM core: 128x128 tile, BK=64, 8 waves (32x64 each, 4x2), 32x32x16 MFMA ----------------
// double-buffered LDS staging (2 x 16KB A + 2 x 16KB B): 1 barrier per K-step.
// A-frag: row=lane&31, k=(lane>>5)*8+j. B-frag: col=lane&31, same k.
// C/D: col=lane&31, row=(reg&3)+8*(reg>>2)+4*(lane>>5)  [verified m74/m101]
__device__ __forceinline__ void gemm_core(const bf16* __restrict__ A, const bf16* __restrict__ Bt,
                                          int row0, int col0, char* AsB, char* BsB, f32x16 acc[2]) {
    int tid = threadIdx.x, wave = tid >> 6, lane = tid & 63;
    int l31 = lane & 31, kh = lane >> 5;
    int rbase = (wave & 3) * 32, cbase = (wave >> 2) * 64;
    const bf16 *Asrc[2], *Bsrc[2];
#pragma unroll
    for (int s = 0; s < 2; ++s) {
        int c = tid + s * 512, r = c >> 3, bk = (c & 7) ^ (r & 7);
        Asrc[s] = A + (size_t)(row0 + r) * 512 + bk * 8;
        Bsrc[s] = Bt + (size_t)(col0 + r) * 512 + bk * 8;
    }
    int wb = wave * 1024;
    // prologue: stage tile 0 into buffer 0
#pragma unroll
    for (int s = 0; s < 2; ++s) {
        glds16(Asrc[s], AsB + s * 8192 + wb);
        glds16(Bsrc[s], BsB + s * 8192 + wb);
    }
#pragma unroll
    for (int it = 0; it < 8; ++it) {
        __syncthreads();   // implicit vmcnt(0): tile `it` resident
        const char* Ac = AsB + (it & 1) * 16384;
        const char* Bc = BsB + (it & 1) * 16384;
        if (it < 7) {
            char* An = AsB + ((it + 1) & 1) * 16384;
            char* Bn = BsB + ((it + 1) & 1) * 16384;
            int k0 = (it + 1) * 64;
#pragma unroll
            for (int s = 0; s < 2; ++s) {
                glds16(Asrc[s] + k0, An + s * 8192 + wb);
                glds16(Bsrc[s] + k0, Bn + s * 8192 + wb);
            }
        }
        bf16x8 af[4], bfr[2][4];
        int arow = rbase + l31;
#pragma unroll
        for (int ks = 0; ks < 4; ++ks)
            af[ks] = *(const bf16x8*)(Ac + (arow * 8 + ((ks * 2 + kh) ^ (arow & 7))) * 16);
#pragma unroll
        for (int ct = 0; ct < 2; ++ct) {
            int col = cbase + ct * 32 + l31;
#pragma unroll
            for (int ks = 0; ks < 4; ++ks)
                bfr[ct][ks] = *(const bf16x8*)(Bc + (col * 8 + ((ks * 2 + kh) ^ (col & 7))) * 16);
        }
#pragma unroll
        for (int ct = 0; ct < 2; ++ct)
#pragma unroll
            for (int ks = 0; ks < 4; ++ks)
                acc[ct] = mfma32(af[ks], bfr[ct][ks], acc[ct]);
    }
}

// fused QKV projections. z=0: q = (Xb@Wq)*cl (pre-scaled); z=1: k = Yb@Wk; z=2: Vt = (Yb@Wv)^T
__global__ __launch_bounds__(512, 2) void proj_qkv(const bf16* __restrict__ Xb, const bf16* __restrict__ Yb,
                                                   const bf16* __restrict__ Wqt, const bf16* __restrict__ Wkt,
                                                   const bf16* __restrict__ Wvt,
                                                   bf16* __restrict__ qb, bf16* __restrict__ kb,
                                                   bf16* __restrict__ Vt) {
    __shared__ char AsB[2 * 16384];
    __shared__ char BsB[2 * 16384];
    int z = blockIdx.z;
    const bf16 *A, *Bt;
    int row0, col0;
    if (z == 0)      { A = Xb;  Bt = Wqt; row0 = blockIdx.x * 128; col0 = blockIdx.y * 128; }
    else if (z == 1) { A = Yb;  Bt = Wkt; row0 = blockIdx.x * 128; col0 = blockIdx.y * 128; }
    else             { A = Wvt; Bt = Yb;  row0 = blockIdx.y * 128; col0 = blockIdx.x * 128; }
    f32x16 acc[2];
#pragma unroll
    for (int i = 0; i < 2; ++i)
#pragma unroll
        for (int r = 0; r < 16; ++r) acc[i][r] = 0.f;
    gemm_core(A, Bt, row0, col0, AsB, BsB, acc);
    int wave = threadIdx.x >> 6, lane = threadIdx.x & 63;
    int l31 = lane & 31, kh = lane >> 5;
    int rbase = (wave & 3) * 32, cbase = (wave >> 2) * 64;
    bf16* dst = (z == 0) ? qb : kb;
    const float cl = 0.06376373228f;    // (1/sqrt(512)) * log2(e)
    float sc = (z == 0) ? cl : 1.0f;
#pragma unroll
    for (int ct = 0; ct < 2; ++ct) {
        int col = col0 + cbase + ct * 32 + l31;
#pragma unroll
        for (int r = 0; r < 16; ++r) {
            int row = row0 + rbase + (r & 3) + 8 * (r >> 2) + 4 * kh;
            bf16 v = (bf16)(acc[ct][r] * sc);
            if (z < 2) dst[(size_t)row * 512 + col] = v;
            else Vt[(size_t)((col >> 10) * 512 + row) * 1024 + (col & 1023)] = v;
        }
    }
}

// all outputs bf16. BIAS: add bias[col]; RELU: max(0,.);
// RESID: 0 none, 1 += fp32 resid[row*512+col], 2 += bf16 resid[row*512+col]
template <int BIAS, int RELU, int RESID>
__global__ __launch_bounds__(512, 2) void gemm_bt(const bf16* __restrict__ A, const bf16* __restrict__ Bt,
                                                  const float* __restrict__ bias,
                                                  const void* __restrict__ resid,
                                                  bf16* __restrict__ Cout) {
    __shared__ char AsB[2 * 16384];
    __shared__ char BsB[2 * 16384];
    int row0 = blockIdx.x * 128, col0 = blockIdx.y * 128;
    f32x16 acc[2];
#pragma unroll
    for (int i = 0; i < 2; ++i)
#pragma unroll
        for (int r = 0; r < 16; ++r) acc[i][r] = 0.f;
    gemm_core(A, Bt, row0, col0, AsB, BsB, acc);
    int wave = threadIdx.x >> 6, lane = threadIdx.x & 63;
    int l31 = lane & 31, kh = lane >> 5;
    int rbase = (wave & 3) * 32, cbase = (wave >> 2) * 64;
#pragma unroll
    for (int ct = 0; ct < 2; ++ct) {
        int col = col0 + cbase + ct * 32 + l31;
        float bv = BIAS ? bias[col] : 0.0f;
#pragma unroll
        for (int r = 0; r < 16; ++r) {
            int row = row0 + rbase + (r & 3) + 8 * (r >> 2) + 4 * kh;
            float v = acc[ct][r] + bv;
            if (RESID == 1) v += ((const float*)resid)[(size_t)row * 512 + col];
            if (RESID == 2) v += (float)((const bf16*)resid)[(size_t)row * 512 + col];
            if (RELU) v = fmaxf(v, 0.0f);
            Cout[(size_t)row * 512 + col] = (bf16)v;
        }
    }
}

// ---------------- attention (R9 shape: best measured) ----------------
// 512 thr (8 waves, wave owns 16 q rows), Q-tile 128, grid 512, K/V double-buffered.
// Q pre-scaled by log2(e)/sqrt(512); lsum via ones-MFMA. bid = ntile*64 + (b*8+h).
__global__ __launch_bounds__(512, 2) void attn(const bf16* __restrict__ Q, const bf16* __restrict__ Kb,
                                               const bf16* __restrict__ Vt, const int* __restrict__ ymask,
                                               bf16* __restrict__ att) {
    __shared__ bf16 Ks[2][64 * 64];     // [key][d], swizzled (2 x 8 KB)
    __shared__ bf16 Vs[2][64 * 64];     // [d][m], swizzled (2 x 8 KB)
    __shared__ bf16 Ps[8][16 * 72];     // per-wave P [q][key], stride 72 (18 KB)
    __shared__ float fmk[1024];         // mask addend per key (4 KB)

    int bid = blockIdx.x;
    int bh = bid & 63, n0 = (bid >> 6) * 128;
    int b = bh >> 3, h = bh & 7;
    int tid = threadIdx.x, wave = tid >> 6, lane = tid & 63;
    int lr = lane & 15, q4 = lane >> 4;

    const int* ymb = ymask + (b << 10);
    fmk[tid]       = ymb[tid]       ? -1e38f : 0.0f;
    fmk[tid + 512] = ymb[tid + 512] ? -1e38f : 0.0f;

    const bf16* qp = Q + (size_t)((b << 10) + n0 + wave * 16 + lr) * 512 + h * 64 + q4 * 8;
    bf16x8 aq0 = *(const bf16x8*)qp;
    bf16x8 aq1 = *(const bf16x8*)(qp + 32);

    bf16 one1 = (bf16)1.0f;
    bf16x8 ones = {one1, one1, one1, one1, one1, one1, one1, one1};

    int r = tid >> 3, bk = (tid & 7) ^ (r & 7);
    const bf16* Ksrc = Kb + (size_t)((b << 10) + r) * 512 + h * 64 + bk * 8;
    const bf16* Vsrc = Vt + (size_t)(b * 512 + h * 64 + r) * 1024 + bk * 8;
    int ldso = tid * 16;

    const f32x4 zv = {0.f, 0.f, 0.f, 0.f};
    f32x4 O[4] = {zv, zv, zv, zv};
    f32x4 O4 = zv;

    glds16(Ksrc, (char*)Ks[0] + ldso);
    glds16(Vsrc, (char*)Vs[0] + ldso);

    for (int it = 0; it < 16; ++it) {
        __syncthreads();
        const char* K_ = (const char*)Ks[it & 1];
        const char* V_ = (const char*)Vs[it & 1];
        if (it < 15) {
            size_t m1 = (size_t)(it + 1) * 64;
            glds16(Ksrc + m1 * 512, (char*)Ks[(it + 1) & 1] + ldso);
            glds16(Vsrc + m1, (char*)Vs[(it + 1) & 1] + ldso);
        }

#pragma unroll
        for (int nt = 0; nt < 4; ++nt) {
            int krow = nt * 16 + lr;
            bf16x8 kf0 = *(const bf16x8*)(K_ + (krow * 8 + (q4 ^ (krow & 7))) * 16);
            bf16x8 kf1 = *(const bf16x8*)(K_ + (krow * 8 + ((4 + q4) ^ (krow & 7))) * 16);
            float fm = fmk[it * 64 + krow];
            f32x4 s = {fm, fm, fm, fm};
            s = mfma16(aq0, kf0, s);
            s = mfma16(aq1, kf1, s);
#pragma unroll
            for (int rr = 0; rr < 4; ++rr)
                Ps[wave][(q4 * 4 + rr) * 72 + krow] = (bf16)exp2f(s[rr]);
        }
        bf16x8 ap0 = *(const bf16x8*)&Ps[wave][lr * 72 + q4 * 8];
        bf16x8 ap1 = *(const bf16x8*)&Ps[wave][lr * 72 + 32 + q4 * 8];
        O4 = mfma16(ap0, ones, O4);
        O4 = mfma16(ap1, ones, O4);
#pragma unroll
        for (int dt = 0; dt < 4; ++dt) {
            int vrow = dt * 16 + lr;
            bf16x8 vf0 = *(const bf16x8*)(V_ + (vrow * 8 + (q4 ^ (vrow & 7))) * 16);
            bf16x8 vf1 = *(const bf16x8*)(V_ + (vrow * 8 + ((4 + q4) ^ (vrow & 7))) * 16);
            O[dt] = mfma16(ap0, vf0, O[dt]);
            O[dt] = mfma16(ap1, vf1, O[dt]);
        }
    }

    float inv[4];
#pragma unroll
    for (int rr = 0; rr < 4; ++rr)
        inv[rr] = (O4[rr] > 0.0f) ? (1.0f / O4[rr]) : 0.0f;
#pragma unroll
    for (int dt = 0; dt < 4; ++dt)
#pragma unroll
        for (int rr = 0; rr < 4; ++rr) {
            int row = n0 + wave * 16 + q4 * 4 + rr;
            att[(size_t)((b << 10) + row) * 512 + h * 64 + dt * 16 + lr] =
                (bf16)(O[dt][rr] * inv[rr]);
        }
}

// ---------------- LayerNorms (128 thr = 1 row; single bf16 input) ----------------
// ln1: obf = LN(o1)  (o1 = x + att@Wo, bf16, residual fused in Wo epilogue)
__global__ __launch_bounds__(128) void ln1_k(const bf16* __restrict__ O1,
                                             const float* __restrict__ g, const float* __restrict__ be,
                                             bf16* __restrict__ Obf) {
    int row = blockIdx.x, t = threadIdx.x;
    bf16x4 av = ((const bf16x4*)(O1 + (size_t)row * 512))[t];
    float4 o = {(float)av.x, (float)av.y, (float)av.z, (float)av.w};
    float s = o.x + o.y + o.z + o.w;
    float sq = o.x * o.x + o.y * o.y + o.z * o.z + o.w * o.w;
#pragma unroll
    for (int off = 1; off < 64; off <<= 1) { s += __shfl_xor(s, off); sq += __shfl_xor(sq, off); }
    __shared__ float ls[2], lq[2];
    if ((t & 63) == 0) { ls[t >> 6] = s; lq[t >> 6] = sq; }
    __syncthreads();
    s = ls[0] + ls[1]; sq = lq[0] + lq[1];
    float mu = s * (1.0f / 512.0f);
    float var = sq * (1.0f / 512.0f) - mu * mu;
    float rs = rsqrtf(var + 1e-5f);
    float4 gv = ((const float4*)g)[t];
    float4 bv = ((const float4*)be)[t];
    bf16x4 b4 = {(bf16)((o.x - mu) * rs * gv.x + bv.x), (bf16)((o.y - mu) * rs * gv.y + bv.y),
                 (bf16)((o.z - mu) * rs * gv.z + bv.z), (bf16)((o.w - mu) * rs * gv.w + bv.w)};
    ((bf16x4*)(Obf + (size_t)row * 512))[t] = b4;
}

// ln2: out = mask ? 0 : LN(S)  (S = obf + ff, bf16, residual fused in FF2 epilogue; fp32 out)
__global__ __launch_bounds__(128) void ln2_k(const bf16* __restrict__ S,
                                             const float* __restrict__ g, const float* __restrict__ be,
                                             const int* __restrict__ xmask, float* __restrict__ out) {
    int row = blockIdx.x, t = threadIdx.x;
    bf16x4 xv = ((const bf16x4*)(S + (size_t)row * 512))[t];
    float4 o = {(float)xv.x, (float)xv.y, (float)xv.z, (float)xv.w};
    float s = o.x + o.y + o.z + o.w;
    float sq = o.x * o.x + o.y * o.y + o.z * o.z + o.w * o.w;
#pragma unroll
    for (int off = 1; off < 64; off <<= 1) { s += __shfl_xor(s, off); sq += __shfl_xor(sq, off); }
    __shared__ float ls[2], lq[2];
    if ((t & 63) == 0) { ls[t >> 6] = s; lq[t >> 6] = sq; }
    __syncthreads();
    s = ls[0] + ls[1]; sq = lq[0] + lq[1];
    float mu = s * (1.0f / 512.0f);
    float var = sq * (1.0f / 512.0f) - mu * mu;
    float rs = rsqrtf(var + 1e-5f);
    int msk = xmask[row];
    float4 gv = ((const float4*)g)[t];
    float4 bv = ((const float4*)be)[t];
    float4 r4 = {(o.x - mu) * rs * gv.x + bv.x, (o.y - mu) * rs * gv.y + bv.y,
                 (o.z - mu) * rs * gv.z + bv.z, (o.w - mu) * rs * gv.w + bv.w};
    if (msk) r4 = {0.f, 0.f, 0.f, 0.f};
    ((float4*)(out + (size_t)row * 512))[t] = r4;
}

// ---------------- launcher ----------------
extern "C" void kernel_launch(void* const* d_in, const int* in_sizes, int n_in,
                              void* d_out, int out_size, void* d_ws, size_t ws_size,
                              hipStream_t stream) {
    const float* x   = (const float*)d_in[0];
    const float* y   = (const float*)d_in[1];
    const int*   xm  = (const int*)d_in[2];
    const int*   ym  = (const int*)d_in[3];
    const float* Wq  = (const float*)d_in[4];
    const float* Wk  = (const float*)d_in[5];
    const float* Wv  = (const float*)d_in[6];
    const float* Wo  = (const float*)d_in[7];
    const float* W1  = (const float*)d_in[8];
    const float* b1  = (const float*)d_in[9];
    const float* W2  = (const float*)d_in[10];
    const float* b2  = (const float*)d_in[11];
    const float* g1  = (const float*)d_in[12];
    const float* be1 = (const float*)d_in[13];
    const float* g2  = (const float*)d_in[14];
    const float* be2 = (const float*)d_in[15];

    char* ws = (char*)d_ws;
    const size_t WT_SZ  = 512 * 512 * sizeof(bf16);             // 512 KB
    const size_t XB_SZ  = (size_t)ROWS_ * 512 * sizeof(bf16);   // 8 MB

    bf16* Wqt = (bf16*)(ws + 0 * WT_SZ);
    bf16* Wkt = (bf16*)(ws + 1 * WT_SZ);
    bf16* Wvt = (bf16*)(ws + 2 * WT_SZ);
    bf16* Wot = (bf16*)(ws + 3 * WT_SZ);
    bf16* W1t = (bf16*)(ws + 4 * WT_SZ);
    bf16* W2t = (bf16*)(ws + 5 * WT_SZ);
    size_t off = 6 * WT_SZ;
    bf16* Xb  = (bf16*)(ws + off); off += XB_SZ;
    bf16* Yb  = (bf16*)(ws + off); off += XB_SZ;
    bf16* qb  = (bf16*)(ws + off); off += XB_SZ;
    bf16* kb  = (bf16*)(ws + off); off += XB_SZ;
    bf16* Vt  = (bf16*)(ws + off); off += XB_SZ;
    // aliases of dead buffers:
    bf16* attb = Xb;   // Xb dead after q projection
    bf16* o1   = kb;   // kb dead after attention:  o1 = x + att@Wo (bf16)
    bf16* obf  = qb;   // qb dead after attention:  obf = LN1(o1)
    bf16* hb   = Yb;   // Yb dead after projections
    bf16* fb   = Vt;   // Vt dead after attention:  fb = obf + FF2-out

    prep<<<8576, 256, 0, stream>>>(x, y, Xb, Yb, Wq, Wk, Wv, Wo, W1, W2,
                                   Wqt, Wkt, Wvt, Wot, W1t, W2t);

    proj_qkv<<<dim3(64, 4, 3), 512, 0, stream>>>(Xb, Yb, Wqt, Wkt, Wvt, qb, kb, Vt);

    attn<<<512, 512, 0, stream>>>(qb, kb, Vt, ym, attb);

    dim3 gg(64, 4);
    gemm_bt<0, 0, 1><<<gg, 512, 0, stream>>>(attb, Wot, nullptr, x, o1);      // o1 = x + att@Wo
    ln1_k<<<ROWS_, 128, 0, stream>>>(o1, g1, be1, obf);                       // obf = LN1(o1)
    gemm_bt<1, 1, 0><<<gg, 512, 0, stream>>>(obf, W1t, b1, nullptr, hb);      // hb = relu(obf@W1+b1)
    gemm_bt<1, 0, 2><<<gg, 512, 0, stream>>>(hb, W2t, b2, obf, fb);           // fb = obf + hb@W2+b2
    ln2_k<<<ROWS_, 128, 0, stream>>>(fb, g2, be2, xm, (float*)d_out);         // out = mask?0:LN2(fb)
}